// Round 1
// baseline (315.478 us; speedup 1.0000x reference)
//
#include <hip/hip_runtime.h>
#include <hip/hip_bf16.h>
#include <math.h>

// Problem constants
#define BSZ   128
#define NP    16      // papers
#define MSZ   64      // sim matrix dim
#define NC    21      // bins / out channels
#define NH    256     // hidden
#define HOUT  16      // output positions per dim
#define NFLAT 5376    // HOUT*NP*NC

// ---------------------------------------------------------------------------
// Kernel 1: RBF soft-histogram -> x [BSZ][HOUT][NFLAT]
// flat index = c*256 + p*16 + wo  (from reference transpose (0,2,4,1,3))
// One block per (b,p). 256 threads, one per (ho,wo) patch.
// ---------------------------------------------------------------------------
__global__ __launch_bounds__(256) void k_rbf(const float* __restrict__ sim,
                                             float* __restrict__ x) {
    int bp = blockIdx.x;            // 0..2047
    int b = bp >> 4, p = bp & 15;

    __shared__ float s[64 * 64];    // 16 KB
    const float* src = sim + (size_t)bp * 4096;
#pragma unroll
    for (int i = 0; i < 16; ++i)
        s[i * 256 + threadIdx.x] = src[i * 256 + threadIdx.x];
    __syncthreads();

    int wo = threadIdx.x & 15, ho = threadIdx.x >> 4;

    float e[16];
#pragma unroll
    for (int i = 0; i < 4; ++i)
#pragma unroll
        for (int j = 0; j < 4; ++j)
            e[i * 4 + j] = s[(ho * 4 + i) * 64 + wo * 4 + j];

    float* xb = x + ((size_t)b * HOUT + ho) * NFLAT + p * 16 + wo;

#pragma unroll
    for (int c = 0; c < NC; ++c) {
        float mu = (c == 0) ? 1.0f : 0.95f - 0.1f * (float)(c - 1);
        float sum = 0.f;
#pragma unroll
        for (int k = 0; k < 16; ++k) {
            float d = e[k] - mu;
            sum += __expf(-50.f * d * d);   // exp(-(d^2)/(2*0.1^2))
        }
        float g = tanhf(0.01f * __logf(fmaxf(sum, 1e-10f)));
        xb[c * 256] = g;
    }
}

// ---------------------------------------------------------------------------
// Kernel 2: h1 = tanh(x @ W_flat + b_flat)
// A: [2048][5376], W: [5376][256], h1: [2048][256]
// 64x64 tile per block, BK=32, 4x4 micro-tile per thread, 256 threads.
// ---------------------------------------------------------------------------
#define BM 64
#define BN 64
#define BK 32

__global__ __launch_bounds__(256) void k_gemm_h1(const float* __restrict__ A,
                                                 const float* __restrict__ W,
                                                 const float* __restrict__ bias,
                                                 float* __restrict__ h1) {
    __shared__ float As[BK][BM + 1];   // +1 pad: conflict-free column writes
    __shared__ float Bs[BK][BN];

    int bm = blockIdx.x;   // 0..31
    int bn = blockIdx.y;   // 0..3
    int tid = threadIdx.x;
    int tx = tid & 15, ty = tid >> 4;

    float acc[4][4] = {{0.f}};

    const float* Ab = A + (size_t)bm * BM * NFLAT;
    const float* Wb = W + bn * BN;

    for (int k0 = 0; k0 < NFLAT; k0 += BK) {
#pragma unroll
        for (int i = 0; i < 8; ++i) {
            int flat = i * 256 + tid;
            int r = flat >> 5, kk = flat & 31;
            As[kk][r] = Ab[(size_t)r * NFLAT + k0 + kk];
        }
#pragma unroll
        for (int i = 0; i < 8; ++i) {
            int flat = i * 256 + tid;
            int kk = flat >> 6, nn = flat & 63;
            Bs[kk][nn] = Wb[(size_t)(k0 + kk) * NH + nn];
        }
        __syncthreads();

#pragma unroll
        for (int kk = 0; kk < BK; ++kk) {
            float a0 = As[kk][ty * 4 + 0];
            float a1 = As[kk][ty * 4 + 1];
            float a2 = As[kk][ty * 4 + 2];
            float a3 = As[kk][ty * 4 + 3];
            float4 bv = *(const float4*)&Bs[kk][tx * 4];
            acc[0][0] += a0 * bv.x; acc[0][1] += a0 * bv.y; acc[0][2] += a0 * bv.z; acc[0][3] += a0 * bv.w;
            acc[1][0] += a1 * bv.x; acc[1][1] += a1 * bv.y; acc[1][2] += a1 * bv.z; acc[1][3] += a1 * bv.w;
            acc[2][0] += a2 * bv.x; acc[2][1] += a2 * bv.y; acc[2][2] += a2 * bv.z; acc[2][3] += a2 * bv.w;
            acc[3][0] += a3 * bv.x; acc[3][1] += a3 * bv.y; acc[3][2] += a3 * bv.z; acc[3][3] += a3 * bv.w;
        }
        __syncthreads();
    }

    int col = bn * BN + tx * 4;
    float b0 = bias[col + 0], b1 = bias[col + 1], b2 = bias[col + 2], b3 = bias[col + 3];
#pragma unroll
    for (int i = 0; i < 4; ++i) {
        int row = bm * BM + ty * 4 + i;
        float4 v;
        v.x = tanhf(acc[i][0] + b0);
        v.y = tanhf(acc[i][1] + b1);
        v.z = tanhf(acc[i][2] + b2);
        v.w = tanhf(acc[i][3] + b3);
        *(float4*)&h1[(size_t)row * NH + col] = v;
    }
}

// ---------------------------------------------------------------------------
// Kernel 3: attention + heads. One block per batch element, 256 threads.
// ---------------------------------------------------------------------------
__global__ __launch_bounds__(256) void k_head(
    const float* __restrict__ h1,      // [BSZ][16][256]
    const float* __restrict__ f_add,   // [BSZ][17]
    const float* __restrict__ W_attn,  // [256]
    const float* __restrict__ b_attn,  // [1]
    const float* __restrict__ W_fadd,  // [17][256]
    const float* __restrict__ b_fadd,  // [256]
    const float* __restrict__ W_d1,    // [256][256]
    const float* __restrict__ b_d1,    // [256]
    const float* __restrict__ W_d2,    // [256][2]
    const float* __restrict__ b_d2,    // [2]
    const float* __restrict__ wfeat,   // [1]
    float* __restrict__ out)           // [512] = log_softmax(128*2) ++ out(128*2)
{
    int b = blockIdx.x;
    int tid = threadIdx.x;

    __shared__ float sh1[16 * 256];    // 16 KB
    __shared__ float slog[16];
    __shared__ float scomb[256];
    __shared__ float r0s[4], r1s[4];

    const float* hb = h1 + (size_t)b * 16 * 256;
#pragma unroll
    for (int i = 0; i < 16; ++i) sh1[i * 256 + tid] = hb[i * 256 + tid];
    __syncthreads();

    // attention logits: 16 threads per ho
    {
        int ho = tid >> 4, j = tid & 15;
        float s = 0.f;
#pragma unroll
        for (int t = 0; t < 16; ++t)
            s += sh1[ho * 256 + j + t * 16] * W_attn[j + t * 16];
        s += __shfl_xor(s, 1); s += __shfl_xor(s, 2);
        s += __shfl_xor(s, 4); s += __shfl_xor(s, 8);
        if (j == 0) slog[ho] = s + b_attn[0];
    }
    __syncthreads();

    // softmax over 16 (redundant per thread)
    float attnv[16];
    {
        float mx = -1e30f;
#pragma unroll
        for (int t = 0; t < 16; ++t) mx = fmaxf(mx, slog[t]);
        float sum = 0.f;
#pragma unroll
        for (int t = 0; t < 16; ++t) { attnv[t] = expf(slog[t] - mx); sum += attnv[t]; }
        float inv = 1.f / sum;
#pragma unroll
        for (int t = 0; t < 16; ++t) attnv[t] *= inv;
    }

    // logits_coarse[tid]
    float lc = 0.f;
#pragma unroll
    for (int t = 0; t < 16; ++t) lc += attnv[t] * sh1[t * 256 + tid];
    lc = tanhf(lc);

    // f_add_proj[tid]
    float fp = b_fadd[tid];
#pragma unroll
    for (int k = 0; k < 17; ++k) fp += f_add[b * 17 + k] * W_fadd[k * 256 + tid];
    fp = tanhf(fp);

    float sg = 1.f / (1.f + expf(-wfeat[0]));
    float comb = (1.f - sg) * fp + sg * lc;
    scomb[tid] = comb;
    __syncthreads();

    // score = tanh(combined @ W_d1 + b_d1)
    float sc = b_d1[tid];
    for (int k = 0; k < 256; ++k) sc += scomb[k] * W_d1[k * 256 + tid];
    sc = tanhf(sc);

    // out_j = score @ W_d2[:,j] + b_d2[j]
    float p0 = sc * W_d2[tid * 2 + 0];
    float p1 = sc * W_d2[tid * 2 + 1];
#pragma unroll
    for (int off = 1; off < 64; off <<= 1) {
        p0 += __shfl_xor(p0, off);
        p1 += __shfl_xor(p1, off);
    }
    if ((tid & 63) == 0) { r0s[tid >> 6] = p0; r1s[tid >> 6] = p1; }
    __syncthreads();

    if (tid == 0) {
        float o0 = r0s[0] + r0s[1] + r0s[2] + r0s[3] + b_d2[0];
        float o1 = r1s[0] + r1s[1] + r1s[2] + r1s[3] + b_d2[1];
        float mx = fmaxf(o0, o1);
        float lse = mx + logf(expf(o0 - mx) + expf(o1 - mx));
        out[b * 2 + 0] = o0 - lse;
        out[b * 2 + 1] = o1 - lse;
        out[256 + b * 2 + 0] = o0;
        out[256 + b * 2 + 1] = o1;
    }
}

// ---------------------------------------------------------------------------
extern "C" void kernel_launch(void* const* d_in, const int* in_sizes, int n_in,
                              void* d_out, int out_size, void* d_ws, size_t ws_size,
                              hipStream_t stream) {
    const float* sim    = (const float*)d_in[0];
    const float* f_add  = (const float*)d_in[1];
    const float* W_flat = (const float*)d_in[2];
    const float* b_flat = (const float*)d_in[3];
    const float* W_attn = (const float*)d_in[4];
    const float* b_attn = (const float*)d_in[5];
    const float* W_fadd = (const float*)d_in[6];
    const float* b_fadd = (const float*)d_in[7];
    const float* W_d1   = (const float*)d_in[8];
    const float* b_d1   = (const float*)d_in[9];
    const float* W_d2   = (const float*)d_in[10];
    const float* b_d2   = (const float*)d_in[11];
    const float* wfeat  = (const float*)d_in[12];
    float* out = (float*)d_out;

    float* x  = (float*)d_ws;                        // [2048][5376] fp32
    float* h1 = x + (size_t)2048 * NFLAT;            // [2048][256]  fp32

    hipLaunchKernelGGL(k_rbf, dim3(2048), dim3(256), 0, stream, sim, x);
    hipLaunchKernelGGL(k_gemm_h1, dim3(32, 4), dim3(256), 0, stream,
                       x, W_flat, b_flat, h1);
    hipLaunchKernelGGL(k_head, dim3(128), dim3(256), 0, stream,
                       h1, f_add, W_attn, b_attn, W_fadd, b_fadd,
                       W_d1, b_d1, W_d2, b_d2, wfeat, out);
}

// Round 5
// 73.136 us; speedup vs baseline: 4.3136x; 4.3136x over previous
//
#include <hip/hip_runtime.h>
#include <hip/hip_bf16.h>
#include <math.h>

// Problem constants
#define BSZ   128
#define NP    16
#define NC    21
#define NH    256
#define HOUT  16
#define NFLAT 5376     // K of the big GEMM (permuted layout k' = p*336 + c*16 + wo)

typedef __attribute__((ext_vector_type(4))) float f32x4;
typedef __attribute__((ext_vector_type(8))) short bf16x8;

__device__ __forceinline__ ushort f2bf(float v) {
    __hip_bfloat16 h = __float2bfloat16(v);
    return *reinterpret_cast<ushort*>(&h);
}

// tanh(0.01*ln(s)) = (s^0.02 - 1)/(s^0.02 + 1)
__device__ __forceinline__ float hist_act(float s) {
    float a = __expf(0.02f * __logf(fmaxf(s, 1e-10f)));
    return (a - 1.f) / (a + 1.f);
}

// ---------------------------------------------------------------------------
// Kernel 0: Wt[n][k'] = bf16(W_flat[k][n]), k' = p*336 + c*16 + wo
// grid (84,4), 256 threads. Coalesced read, LDS transpose, 32B-chunk writes.
// ---------------------------------------------------------------------------
__global__ __launch_bounds__(256) void k_prep(const float* __restrict__ W,
                                              ushort* __restrict__ Wt) {
    __shared__ ushort ldsT[64][72];
    int k0 = blockIdx.x * 64, n0 = blockIdx.y * 64;
    int tid = threadIdx.x;
    int nl = tid & 63, kq = tid >> 6;
#pragma unroll
    for (int i = 0; i < 16; ++i) {
        int kl = i * 4 + kq;
        ldsT[nl][kl] = f2bf(W[(size_t)(k0 + kl) * NH + n0 + nl]);
    }
    __syncthreads();
    int n = tid >> 2, q = tid & 3;
    int k = k0 + q * 16;
    int c = k >> 8, p = (k >> 4) & 15;
    ushort* dst = Wt + (size_t)(n0 + n) * NFLAT + p * 336 + c * 16;
    const ushort* srow = &ldsT[n][q * 16];
#pragma unroll
    for (int i = 0; i < 8; ++i) {
        ushort2 v; v.x = srow[2 * i]; v.y = srow[2 * i + 1];
        ((ushort2*)dst)[i] = v;
    }
}

// ---------------------------------------------------------------------------
// Kernel 1: RBF soft-histogram -> x bf16 [2048][5376] (permuted k')
// One block per (b,p). Recurrence: f_{c+1}=f_c*g_c, g_{c+1}=g_c*e^-1.
// ---------------------------------------------------------------------------
__global__ __launch_bounds__(256) void k_rbf(const float* __restrict__ sim,
                                             ushort* __restrict__ x) {
    int bp = blockIdx.x, b = bp >> 4, p = bp & 15;
    __shared__ float s[4096];
    __shared__ ushort stage[16 * 336];
    const float* src = sim + (size_t)bp * 4096;
    int tid = threadIdx.x;
#pragma unroll
    for (int i = 0; i < 16; ++i) s[i * 256 + tid] = src[i * 256 + tid];
    __syncthreads();

    int wo = tid & 15, ho = tid >> 4;
    float f[16], g[16];
    float sum0 = 0.f;
#pragma unroll
    for (int i = 0; i < 4; ++i)
#pragma unroll
        for (int j = 0; j < 4; ++j) {
            float e = s[(ho * 4 + i) * 64 + wo * 4 + j];
            int k2 = i * 4 + j;
            float d0 = e - 1.0f;
            sum0 += __expf(-50.f * d0 * d0);
            float d1 = e - 0.95f;
            f[k2] = __expf(-50.f * d1 * d1);
            g[k2] = __expf(-10.f * d1 - 0.5f);
        }

    stage[ho * 336 + wo] = f2bf(hist_act(sum0));
#pragma unroll
    for (int c = 1; c < 21; ++c) {
        float sv = 0.f;
#pragma unroll
        for (int k2 = 0; k2 < 16; ++k2) sv += f[k2];
        stage[ho * 336 + c * 16 + wo] = f2bf(hist_act(sv));
        if (c < 20) {
#pragma unroll
            for (int k2 = 0; k2 < 16; ++k2) { f[k2] *= g[k2]; g[k2] *= 0.36787944117f; }
        }
    }
    __syncthreads();

    // cooperative coalesced write-out: 2688 dwords
    const uint* ssrc = (const uint*)stage;
    char* xb = (char*)x;
#pragma unroll
    for (int it = 0; it < 11; ++it) {
        int i = it * 256 + tid;
        if (i < 2688) {
            int row = i / 168;
            int jc = i - row * 168;
            *(uint*)(xb + ((size_t)(b * 16 + row) * NFLAT + p * 336) * 2 + jc * 4) = ssrc[i];
        }
    }
}

// ---------------------------------------------------------------------------
// Kernel 2: MFMA GEMM, split-K. A[2048][5376] bf16, Bt[256][5376] bf16.
// partial[sk][row][col] fp32.  BM=64 BN=128 BK=64, 512 thr (8 waves, 16x64 each).
// LDS XOR-swizzled on 16B slots; reg-staged double buffer, 1 barrier/tile.
// ---------------------------------------------------------------------------
__global__ __launch_bounds__(512) void k_gemm(const ushort* __restrict__ A,
                                              const ushort* __restrict__ Bt,
                                              float* __restrict__ part) {
    __shared__ __align__(16) char lds[2][24576];   // per buf: A 8KB | B 16KB
    int bm = blockIdx.x, bn = blockIdx.y, sk = blockIdx.z;
    int t = threadIdx.x;
    int l = t & 63, w = t >> 6;
    int wr = w >> 1, wc = w & 1;
    int row0 = bm * 64, col0 = bn * 128;
    int kbase = sk * 1344;

    // staging assignment: A 512 chunks (1/thr), B 1024 chunks (2/thr)
    int ar = t >> 3, s8 = t & 7;
    int br1 = ar + 64;
    int wA  = ar * 128 + ((s8 ^ (ar & 7)) << 4);
    int wB0 = 8192 + ar * 128 + ((s8 ^ (ar & 7)) << 4);
    int wB1 = 8192 + br1 * 128 + ((s8 ^ (br1 & 7)) << 4);

    const ushort* gA  = A  + (size_t)(row0 + ar) * NFLAT + kbase + s8 * 8;
    const ushort* gB0 = Bt + (size_t)(col0 + ar) * NFLAT + kbase + s8 * 8;
    const ushort* gB1 = Bt + (size_t)(col0 + br1) * NFLAT + kbase + s8 * 8;

    int arow = wr * 16 + (l & 15);
    int lk = l >> 4;
    int brow0 = wc * 64 + (l & 15);

    f32x4 acc[4];
#pragma unroll
    for (int n = 0; n < 4; ++n) acc[n] = (f32x4){0.f, 0.f, 0.f, 0.f};

    uint4 ra = *(const uint4*)gA;
    uint4 rb0 = *(const uint4*)gB0;
    uint4 rb1 = *(const uint4*)gB1;
    *(uint4*)(&lds[0][wA])  = ra;
    *(uint4*)(&lds[0][wB0]) = rb0;
    *(uint4*)(&lds[0][wB1]) = rb1;
    __syncthreads();

#pragma unroll 1
    for (int tt = 0; tt < 21; ++tt) {
        if (tt < 20) {   // issue next-tile loads early; latency hides under MFMA
            ra  = *(const uint4*)(gA  + (tt + 1) * 64);
            rb0 = *(const uint4*)(gB0 + (tt + 1) * 64);
            rb1 = *(const uint4*)(gB1 + (tt + 1) * 64);
        }
        const char* As = lds[tt & 1];
        const char* Bs = As + 8192;
#pragma unroll
        for (int ks = 0; ks < 2; ++ks) {
            int slot = (ks << 2) | lk;
            bf16x8 a = *(const bf16x8*)(As + arow * 128 + ((slot ^ (arow & 7)) << 4));
#pragma unroll
            for (int n = 0; n < 4; ++n) {
                int brow = brow0 + n * 16;
                bf16x8 bb = *(const bf16x8*)(Bs + brow * 128 + ((slot ^ (brow & 7)) << 4));
                acc[n] = __builtin_amdgcn_mfma_f32_16x16x32_bf16(a, bb, acc[n], 0, 0, 0);
            }
        }
        if (tt < 20) {   // write other buffer (nobody reads it this iter)
            char* nb = lds[(tt + 1) & 1];
            *(uint4*)(nb + wA)  = ra;
            *(uint4*)(nb + wB0) = rb0;
            *(uint4*)(nb + wB1) = rb1;
        }
        __syncthreads();
    }

    // store partials: C row=(lane>>4)*4+j (+m base), col=lane&15 (+n base)
    float* pp = part + (size_t)sk * 2048 * 256;
    int crow = row0 + wr * 16 + lk * 4;
#pragma unroll
    for (int n = 0; n < 4; ++n) {
        int ccol = col0 + wc * 64 + n * 16 + (l & 15);
#pragma unroll
        for (int j = 0; j < 4; ++j)
            pp[(size_t)(crow + j) * 256 + ccol] = acc[n][j];
    }
}

// ---------------------------------------------------------------------------
// Kernel 3: fused split-K reduce + bias + tanh + attention + heads.
// One block per batch element, 256 threads.
// ---------------------------------------------------------------------------
__global__ __launch_bounds__(256) void k_head(
    const float* __restrict__ part,    // [4][2048][256]
    const float* __restrict__ b_flat,  // [256]
    const float* __restrict__ f_add,   // [BSZ][17]
    const float* __restrict__ W_attn,  // [256]
    const float* __restrict__ b_attn,  // [1]
    const float* __restrict__ W_fadd,  // [17][256]
    const float* __restrict__ b_fadd,  // [256]
    const float* __restrict__ W_d1,    // [256][256]
    const float* __restrict__ b_d1,    // [256]
    const float* __restrict__ W_d2,    // [256][2]
    const float* __restrict__ b_d2,    // [2]
    const float* __restrict__ wfeat,   // [1]
    float* __restrict__ out)           // [512]
{
    int b = blockIdx.x;
    int tid = threadIdx.x;

    __shared__ float sh1[16 * 256];
    __shared__ float slog[16];
    __shared__ float scomb[256];
    __shared__ float r0s[4], r1s[4];

    // h1 = tanh(sum_sk partial + bias)
#pragma unroll
    for (int i = 0; i < 16; ++i) {
        size_t row = (size_t)(b * 16 + i) * 256 + tid;
        float v = b_flat[tid];
        v += part[row] + part[524288 + row] + part[2 * 524288 + row] + part[3 * 524288 + row];
        sh1[i * 256 + tid] = tanhf(v);
    }
    __syncthreads();

    // attention logits
    {
        int ho = tid >> 4, j = tid & 15;
        float s = 0.f;
#pragma unroll
        for (int t2 = 0; t2 < 16; ++t2)
            s += sh1[ho * 256 + j + t2 * 16] * W_attn[j + t2 * 16];
        s += __shfl_xor(s, 1); s += __shfl_xor(s, 2);
        s += __shfl_xor(s, 4); s += __shfl_xor(s, 8);
        if (j == 0) slog[ho] = s + b_attn[0];
    }
    __syncthreads();

    float attnv[16];
    {
        float mx = -1e30f;
#pragma unroll
        for (int t2 = 0; t2 < 16; ++t2) mx = fmaxf(mx, slog[t2]);
        float sum = 0.f;
#pragma unroll
        for (int t2 = 0; t2 < 16; ++t2) { attnv[t2] = expf(slog[t2] - mx); sum += attnv[t2]; }
        float inv = 1.f / sum;
#pragma unroll
        for (int t2 = 0; t2 < 16; ++t2) attnv[t2] *= inv;
    }

    float lc = 0.f;
#pragma unroll
    for (int t2 = 0; t2 < 16; ++t2) lc += attnv[t2] * sh1[t2 * 256 + tid];
    lc = tanhf(lc);

    float fp = b_fadd[tid];
#pragma unroll
    for (int k = 0; k < 17; ++k) fp += f_add[b * 17 + k] * W_fadd[k * 256 + tid];
    fp = tanhf(fp);

    float sg = 1.f / (1.f + expf(-wfeat[0]));
    scomb[tid] = (1.f - sg) * fp + sg * lc;
    __syncthreads();

    float sc = b_d1[tid];
    for (int k = 0; k < 256; ++k) sc += scomb[k] * W_d1[k * 256 + tid];
    sc = tanhf(sc);

    float p0 = sc * W_d2[tid * 2 + 0];
    float p1 = sc * W_d2[tid * 2 + 1];
#pragma unroll
    for (int off = 1; off < 64; off <<= 1) {
        p0 += __shfl_xor(p0, off);
        p1 += __shfl_xor(p1, off);
    }
    if ((tid & 63) == 0) { r0s[tid >> 6] = p0; r1s[tid >> 6] = p1; }
    __syncthreads();

    if (tid == 0) {
        float o0 = r0s[0] + r0s[1] + r0s[2] + r0s[3] + b_d2[0];
        float o1 = r1s[0] + r1s[1] + r1s[2] + r1s[3] + b_d2[1];
        float mx = fmaxf(o0, o1);
        float lse = mx + logf(expf(o0 - mx) + expf(o1 - mx));
        out[b * 2 + 0] = o0 - lse;
        out[b * 2 + 1] = o1 - lse;
        out[256 + b * 2 + 0] = o0;
        out[256 + b * 2 + 1] = o1;
    }
}

// ---------------------------------------------------------------------------
extern "C" void kernel_launch(void* const* d_in, const int* in_sizes, int n_in,
                              void* d_out, int out_size, void* d_ws, size_t ws_size,
                              hipStream_t stream) {
    const float* sim    = (const float*)d_in[0];
    const float* f_add  = (const float*)d_in[1];
    const float* W_flat = (const float*)d_in[2];
    const float* b_flat = (const float*)d_in[3];
    const float* W_attn = (const float*)d_in[4];
    const float* b_attn = (const float*)d_in[5];
    const float* W_fadd = (const float*)d_in[6];
    const float* b_fadd = (const float*)d_in[7];
    const float* W_d1   = (const float*)d_in[8];
    const float* b_d1   = (const float*)d_in[9];
    const float* W_d2   = (const float*)d_in[10];
    const float* b_d2   = (const float*)d_in[11];
    const float* wfeat  = (const float*)d_in[12];
    float* out = (float*)d_out;

    ushort* x  = (ushort*)d_ws;                       // [2048][5376] bf16  (22.0 MB)
    ushort* Wt = x + (size_t)2048 * NFLAT;            // [256][5376]  bf16  (2.75 MB)
    float* part = (float*)(Wt + (size_t)256 * NFLAT); // [4][2048][256] f32 (8 MB)

    hipLaunchKernelGGL(k_prep, dim3(84, 4), dim3(256), 0, stream, W_flat, Wt);
    hipLaunchKernelGGL(k_rbf, dim3(2048), dim3(256), 0, stream, sim, x);
    hipLaunchKernelGGL(k_gemm, dim3(32, 2, 4), dim3(512), 0, stream, x, Wt, part);
    hipLaunchKernelGGL(k_head, dim3(128), dim3(256), 0, stream,
                       part, b_flat, f_add, W_attn, b_attn, W_fadd, b_fadd,
                       W_d1, b_d1, W_d2, b_d2, wfeat, out);
}

// Round 6
// 62.420 us; speedup vs baseline: 5.0541x; 1.1717x over previous
//
#include <hip/hip_runtime.h>
#include <hip/hip_bf16.h>
#include <math.h>

// Problem constants
#define BSZ   128
#define NP    16
#define NC    21
#define NH    256
#define HOUT  16
#define NFLAT 5376     // K of the big GEMM (permuted layout k' = p*336 + c*16 + wo)

typedef __attribute__((ext_vector_type(4))) float f32x4;
typedef __attribute__((ext_vector_type(8))) short bf16x8;

__device__ __forceinline__ ushort f2bf(float v) {
    __hip_bfloat16 h = __float2bfloat16(v);
    return *reinterpret_cast<ushort*>(&h);
}

// tanh(0.01*ln(s)) = (s^0.02 - 1)/(s^0.02 + 1), division via v_rcp_f32
__device__ __forceinline__ float hist_act(float s) {
    float a = __expf(0.02f * __logf(fmaxf(s, 1e-10f)));
    return (a - 1.f) * __builtin_amdgcn_rcpf(a + 1.f);
}

// tanh(x) = 1 - 2/(e^{2x}+1)  (~5 inst vs ~40 for ocml tanhf)
__device__ __forceinline__ float fast_tanh(float v) {
    float e = __expf(2.f * v);
    return 1.f - 2.f * __builtin_amdgcn_rcpf(e + 1.f);
}

// ---------------------------------------------------------------------------
// Kernel 1 (fused): blocks 0..2047  -> RBF soft-histogram for (b,p)
//                   blocks 2048..2383 -> W_flat transpose/convert to Wt
// x layout: [2048][5376] bf16, k' = p*336 + c*16 + wo
// ---------------------------------------------------------------------------
__global__ __launch_bounds__(256) void k_pre(const float* __restrict__ sim,
                                             ushort* __restrict__ x,
                                             const float* __restrict__ W,
                                             ushort* __restrict__ Wt) {
    int tid = threadIdx.x;

    if (blockIdx.x >= 2048) {
        // ---- prep: Wt[n][k'] = bf16(W[k][n]) ----
        __shared__ ushort ldsT[64][72];
        int pb = blockIdx.x - 2048;          // 0..335
        int kb = pb % 84, nb = pb / 84;
        int k0 = kb * 64, n0 = nb * 64;
        int nl = tid & 63, kq = tid >> 6;
#pragma unroll
        for (int i = 0; i < 16; ++i) {
            int kl = i * 4 + kq;
            ldsT[nl][kl] = f2bf(W[(size_t)(k0 + kl) * NH + n0 + nl]);
        }
        __syncthreads();
        int n = tid >> 2, q = tid & 3;
        int k = k0 + q * 16;
        int c = k >> 8, p = (k >> 4) & 15;
        ushort* dst = Wt + (size_t)(n0 + n) * NFLAT + p * 336 + c * 16;
        const ushort* srow = &ldsT[n][q * 16];
#pragma unroll
        for (int i = 0; i < 8; ++i) {
            ushort2 v; v.x = srow[2 * i]; v.y = srow[2 * i + 1];
            ((ushort2*)dst)[i] = v;
        }
        return;
    }

    // ---- RBF ----
    int bp = blockIdx.x, b = bp >> 4, p = bp & 15;
    __shared__ float s[4096];
    __shared__ ushort stage[16 * 336];
    const float* src = sim + (size_t)bp * 4096;
#pragma unroll
    for (int i = 0; i < 16; ++i) s[i * 256 + tid] = src[i * 256 + tid];
    __syncthreads();

    int wo = tid & 15, ho = tid >> 4;
    float f[16], g[16];
    float sum0 = 0.f;
#pragma unroll
    for (int i = 0; i < 4; ++i)
#pragma unroll
        for (int j = 0; j < 4; ++j) {
            float e = s[(ho * 4 + i) * 64 + wo * 4 + j];
            int k2 = i * 4 + j;
            float d0 = e - 1.0f;
            sum0 += __expf(-50.f * d0 * d0);
            float d1 = e - 0.95f;
            f[k2] = __expf(-50.f * d1 * d1);
            g[k2] = __expf(-10.f * d1 - 0.5f);
        }

    stage[ho * 336 + wo] = f2bf(hist_act(sum0));
#pragma unroll
    for (int c = 1; c < 21; ++c) {
        float sv = 0.f;
#pragma unroll
        for (int k2 = 0; k2 < 16; ++k2) sv += f[k2];
        stage[ho * 336 + c * 16 + wo] = f2bf(hist_act(sv));
        if (c < 20) {
#pragma unroll
            for (int k2 = 0; k2 < 16; ++k2) { f[k2] *= g[k2]; g[k2] *= 0.36787944117f; }
        }
    }
    __syncthreads();

    // cooperative coalesced write-out: 2688 dwords
    const uint* ssrc = (const uint*)stage;
    char* xb = (char*)x;
#pragma unroll
    for (int it = 0; it < 11; ++it) {
        int i = it * 256 + tid;
        if (i < 2688) {
            int row = i / 168;
            int jc = i - row * 168;
            *(uint*)(xb + ((size_t)(b * 16 + row) * NFLAT + p * 336) * 2 + jc * 4) = ssrc[i];
        }
    }
}

// ---------------------------------------------------------------------------
// Kernel 2: MFMA GEMM, split-K. A[2048][5376] bf16, Bt[256][5376] bf16.
// partial[sk][row][col] fp32.  BM=64 BN=128 BK=64, 512 thr (8 waves, 16x64 each).
// LDS XOR-swizzled on 16B slots; reg-staged double buffer, 1 barrier/tile.
// ---------------------------------------------------------------------------
__global__ __launch_bounds__(512) void k_gemm(const ushort* __restrict__ A,
                                              const ushort* __restrict__ Bt,
                                              float* __restrict__ part) {
    __shared__ __align__(16) char lds[2][24576];   // per buf: A 8KB | B 16KB
    int bm = blockIdx.x, bn = blockIdx.y, sk = blockIdx.z;
    int t = threadIdx.x;
    int l = t & 63, w = t >> 6;
    int wr = w >> 1, wc = w & 1;
    int row0 = bm * 64, col0 = bn * 128;
    int kbase = sk * 1344;

    // staging assignment: A 512 chunks (1/thr), B 1024 chunks (2/thr)
    int ar = t >> 3, s8 = t & 7;
    int br1 = ar + 64;
    int wA  = ar * 128 + ((s8 ^ (ar & 7)) << 4);
    int wB0 = 8192 + ar * 128 + ((s8 ^ (ar & 7)) << 4);
    int wB1 = 8192 + br1 * 128 + ((s8 ^ (br1 & 7)) << 4);

    const ushort* gA  = A  + (size_t)(row0 + ar) * NFLAT + kbase + s8 * 8;
    const ushort* gB0 = Bt + (size_t)(col0 + ar) * NFLAT + kbase + s8 * 8;
    const ushort* gB1 = Bt + (size_t)(col0 + br1) * NFLAT + kbase + s8 * 8;

    int arow = wr * 16 + (l & 15);
    int lk = l >> 4;
    int brow0 = wc * 64 + (l & 15);

    f32x4 acc[4];
#pragma unroll
    for (int n = 0; n < 4; ++n) acc[n] = (f32x4){0.f, 0.f, 0.f, 0.f};

    uint4 ra = *(const uint4*)gA;
    uint4 rb0 = *(const uint4*)gB0;
    uint4 rb1 = *(const uint4*)gB1;
    *(uint4*)(&lds[0][wA])  = ra;
    *(uint4*)(&lds[0][wB0]) = rb0;
    *(uint4*)(&lds[0][wB1]) = rb1;
    __syncthreads();

#pragma unroll 1
    for (int tt = 0; tt < 21; ++tt) {
        if (tt < 20) {   // issue next-tile loads early; latency hides under MFMA
            ra  = *(const uint4*)(gA  + (tt + 1) * 64);
            rb0 = *(const uint4*)(gB0 + (tt + 1) * 64);
            rb1 = *(const uint4*)(gB1 + (tt + 1) * 64);
        }
        const char* As = lds[tt & 1];
        const char* Bs = As + 8192;
#pragma unroll
        for (int ks = 0; ks < 2; ++ks) {
            int slot = (ks << 2) | lk;
            bf16x8 a = *(const bf16x8*)(As + arow * 128 + ((slot ^ (arow & 7)) << 4));
#pragma unroll
            for (int n = 0; n < 4; ++n) {
                int brow = brow0 + n * 16;
                bf16x8 bb = *(const bf16x8*)(Bs + brow * 128 + ((slot ^ (brow & 7)) << 4));
                acc[n] = __builtin_amdgcn_mfma_f32_16x16x32_bf16(a, bb, acc[n], 0, 0, 0);
            }
        }
        if (tt < 20) {   // write other buffer (nobody reads it this iter)
            char* nb = lds[(tt + 1) & 1];
            *(uint4*)(nb + wA)  = ra;
            *(uint4*)(nb + wB0) = rb0;
            *(uint4*)(nb + wB1) = rb1;
        }
        __syncthreads();
    }

    // store partials: C row=(lane>>4)*4+j (+m base), col=lane&15 (+n base)
    float* pp = part + (size_t)sk * 2048 * 256;
    int crow = row0 + wr * 16 + lk * 4;
#pragma unroll
    for (int n = 0; n < 4; ++n) {
        int ccol = col0 + wc * 64 + n * 16 + (l & 15);
#pragma unroll
        for (int j = 0; j < 4; ++j)
            pp[(size_t)(crow + j) * 256 + ccol] = acc[n][j];
    }
}

// ---------------------------------------------------------------------------
// Kernel 3: fused split-K reduce + bias + tanh + attention + heads.
// One block per batch element, 256 threads. Fast-math transcendentals.
// ---------------------------------------------------------------------------
__global__ __launch_bounds__(256) void k_head(
    const float* __restrict__ part,    // [4][2048][256]
    const float* __restrict__ b_flat,  // [256]
    const float* __restrict__ f_add,   // [BSZ][17]
    const float* __restrict__ W_attn,  // [256]
    const float* __restrict__ b_attn,  // [1]
    const float* __restrict__ W_fadd,  // [17][256]
    const float* __restrict__ b_fadd,  // [256]
    const float* __restrict__ W_d1,    // [256][256]
    const float* __restrict__ b_d1,    // [256]
    const float* __restrict__ W_d2,    // [256][2]
    const float* __restrict__ b_d2,    // [2]
    const float* __restrict__ wfeat,   // [1]
    float* __restrict__ out)           // [512]
{
    int b = blockIdx.x;
    int tid = threadIdx.x;

    __shared__ float sh1[16 * 256];
    __shared__ float slog[16];
    __shared__ float scomb[256];
    __shared__ float r0s[4], r1s[4];

    // h1 = tanh(sum_sk partial + bias)
#pragma unroll
    for (int i = 0; i < 16; ++i) {
        size_t row = (size_t)(b * 16 + i) * 256 + tid;
        float v = b_flat[tid];
        v += part[row] + part[524288 + row] + part[2 * 524288 + row] + part[3 * 524288 + row];
        sh1[i * 256 + tid] = fast_tanh(v);
    }
    __syncthreads();

    // attention logits
    {
        int ho = tid >> 4, j = tid & 15;
        float s = 0.f;
#pragma unroll
        for (int t2 = 0; t2 < 16; ++t2)
            s += sh1[ho * 256 + j + t2 * 16] * W_attn[j + t2 * 16];
        s += __shfl_xor(s, 1); s += __shfl_xor(s, 2);
        s += __shfl_xor(s, 4); s += __shfl_xor(s, 8);
        if (j == 0) slog[ho] = s + b_attn[0];
    }
    __syncthreads();

    float attnv[16];
    {
        float mx = -1e30f;
#pragma unroll
        for (int t2 = 0; t2 < 16; ++t2) mx = fmaxf(mx, slog[t2]);
        float sum = 0.f;
#pragma unroll
        for (int t2 = 0; t2 < 16; ++t2) { attnv[t2] = __expf(slog[t2] - mx); sum += attnv[t2]; }
        float inv = __builtin_amdgcn_rcpf(sum);
#pragma unroll
        for (int t2 = 0; t2 < 16; ++t2) attnv[t2] *= inv;
    }

    float lc = 0.f;
#pragma unroll
    for (int t2 = 0; t2 < 16; ++t2) lc += attnv[t2] * sh1[t2 * 256 + tid];
    lc = fast_tanh(lc);

    float fp = b_fadd[tid];
#pragma unroll
    for (int k = 0; k < 17; ++k) fp += f_add[b * 17 + k] * W_fadd[k * 256 + tid];
    fp = fast_tanh(fp);

    float sg = __builtin_amdgcn_rcpf(1.f + __expf(-wfeat[0]));
    scomb[tid] = (1.f - sg) * fp + sg * lc;
    __syncthreads();

    float sc = b_d1[tid];
#pragma unroll 8
    for (int k = 0; k < 256; ++k) sc += scomb[k] * W_d1[k * 256 + tid];
    sc = fast_tanh(sc);

    float p0 = sc * W_d2[tid * 2 + 0];
    float p1 = sc * W_d2[tid * 2 + 1];
#pragma unroll
    for (int off = 1; off < 64; off <<= 1) {
        p0 += __shfl_xor(p0, off);
        p1 += __shfl_xor(p1, off);
    }
    if ((tid & 63) == 0) { r0s[tid >> 6] = p0; r1s[tid >> 6] = p1; }
    __syncthreads();

    if (tid == 0) {
        float o0 = r0s[0] + r0s[1] + r0s[2] + r0s[3] + b_d2[0];
        float o1 = r1s[0] + r1s[1] + r1s[2] + r1s[3] + b_d2[1];
        float mx = fmaxf(o0, o1);
        float lse = mx + __logf(__expf(o0 - mx) + __expf(o1 - mx));
        out[b * 2 + 0] = o0 - lse;
        out[b * 2 + 1] = o1 - lse;
        out[256 + b * 2 + 0] = o0;
        out[256 + b * 2 + 1] = o1;
    }
}

// ---------------------------------------------------------------------------
extern "C" void kernel_launch(void* const* d_in, const int* in_sizes, int n_in,
                              void* d_out, int out_size, void* d_ws, size_t ws_size,
                              hipStream_t stream) {
    const float* sim    = (const float*)d_in[0];
    const float* f_add  = (const float*)d_in[1];
    const float* W_flat = (const float*)d_in[2];
    const float* b_flat = (const float*)d_in[3];
    const float* W_attn = (const float*)d_in[4];
    const float* b_attn = (const float*)d_in[5];
    const float* W_fadd = (const float*)d_in[6];
    const float* b_fadd = (const float*)d_in[7];
    const float* W_d1   = (const float*)d_in[8];
    const float* b_d1   = (const float*)d_in[9];
    const float* W_d2   = (const float*)d_in[10];
    const float* b_d2   = (const float*)d_in[11];
    const float* wfeat  = (const float*)d_in[12];
    float* out = (float*)d_out;

    ushort* x  = (ushort*)d_ws;                       // [2048][5376] bf16  (22.0 MB)
    ushort* Wt = x + (size_t)2048 * NFLAT;            // [256][5376]  bf16  (2.75 MB)
    float* part = (float*)(Wt + (size_t)256 * NFLAT); // [4][2048][256] f32 (8 MB)

    hipLaunchKernelGGL(k_pre, dim3(2048 + 336), dim3(256), 0, stream, sim, x, W_flat, Wt);
    hipLaunchKernelGGL(k_gemm, dim3(32, 2, 4), dim3(512), 0, stream, x, Wt, part);
    hipLaunchKernelGGL(k_head, dim3(128), dim3(256), 0, stream,
                       part, b_flat, f_add, W_attn, b_attn, W_fadd, b_fadd,
                       W_d1, b_d1, W_d2, b_d2, wfeat, out);
}